// Round 1
// baseline (427.739 us; speedup 1.0000x reference)
//
#include <hip/hip_runtime.h>
#include <math.h>

#define BB 64
#define SS 1024
#define DD 32
#define HH 2
#define DHH 16
#define VV 28
#define TK 256

// ---------------- kernel 1: per-row extended last index ----------------
__global__ void k_last(const float* __restrict__ mask, int* __restrict__ e) {
    int b = blockIdx.x;
    int lm = -1;
    for (int s = threadIdx.x; s < SS; s += blockDim.x) {
        if (mask[b * SS + s] != 0.0f) lm = s;   // strided; reduce max below
    }
    __shared__ int red[256];
    red[threadIdx.x] = lm;
    __syncthreads();
    for (int off = 128; off > 0; off >>= 1) {
        if (threadIdx.x < off) red[threadIdx.x] = max(red[threadIdx.x], red[threadIdx.x + off]);
        __syncthreads();
    }
    if (threadIdx.x == 0) {
        int last = red[0];
        int ee = last;
        if (last < SS - 1) ee = min(last + 3, SS - 1);
        e[b] = ee;   // nm[s] = (s <= e)
    }
}

// ---------------- kernel 2: h = (emb[x]+pe)*nm ; q,k,v projections ----------------
__global__ void k_qkv(const int* __restrict__ x, const float* __restrict__ emb,
                      const float* __restrict__ pe,
                      const float* __restrict__ wq, const float* __restrict__ bq,
                      const float* __restrict__ wk, const float* __restrict__ bk,
                      const float* __restrict__ wv, const float* __restrict__ bv,
                      const int* __restrict__ e,
                      float* __restrict__ q, float* __restrict__ k, float* __restrict__ v) {
    __shared__ float sWq[DD * DD], sWk[DD * DD], sWv[DD * DD];
    __shared__ float sBq[DD], sBk[DD], sBv[DD];
    for (int i = threadIdx.x; i < DD * DD; i += blockDim.x) {
        sWq[i] = wq[i]; sWk[i] = wk[i]; sWv[i] = wv[i];
    }
    if (threadIdx.x < DD) {
        sBq[threadIdx.x] = bq[threadIdx.x];
        sBk[threadIdx.x] = bk[threadIdx.x];
        sBv[threadIdx.x] = bv[threadIdx.x];
    }
    __syncthreads();

    int idx = blockIdx.x * blockDim.x + threadIdx.x;    // [0, B*S)
    int b = idx / SS, s = idx % SS;
    float nm = (s <= e[b]) ? 1.0f : 0.0f;
    int tok = x[idx];

    float h[DD];
#pragma unroll
    for (int i = 0; i < DD; i++) h[i] = (emb[tok * DD + i] + pe[s * DD + i]) * nm;

#pragma unroll
    for (int i = 0; i < DD; i++) {
        float aq = sBq[i], ak = sBk[i], av = sBv[i];
#pragma unroll
        for (int j = 0; j < DD; j++) {
            aq += h[j] * sWq[i * DD + j];
            ak += h[j] * sWk[i * DD + j];
            av += h[j] * sWv[i * DD + j];
        }
        q[(size_t)idx * DD + i] = aq;
        k[(size_t)idx * DD + i] = ak;
        v[(size_t)idx * DD + i] = av;
    }
}

// ---------------- kernel 3: flash-style attention, 1 thread per (b,h,query) ----------------
__global__ void k_attn(const float* __restrict__ q, const float* __restrict__ k,
                       const float* __restrict__ v, const int* __restrict__ e,
                       float* __restrict__ o) {
    int bh = blockIdx.y;
    int b = bh / HH, hh = bh % HH;
    int qi = blockIdx.x * blockDim.x + threadIdx.x;    // query position

    const float* qp = q + ((size_t)(b * SS + qi)) * DD + hh * DHH;
    float qv[DHH];
#pragma unroll
    for (int i = 0; i < DHH; i++) qv[i] = qp[i] * 0.25f;   // 1/sqrt(DH)

    int kmax = e[b] + 1;   // prefix mask: keys >= kmax get -1e9 -> exp == 0 exactly

    __shared__ float sk[TK][DHH];
    __shared__ float sv[TK][DHH];

    float m = -1e30f, l = 0.0f;
    float acc[DHH];
#pragma unroll
    for (int i = 0; i < DHH; i++) acc[i] = 0.0f;

    for (int kt = 0; kt < kmax; kt += TK) {
        int kn = min(TK, kmax - kt);
        __syncthreads();
        if (threadIdx.x < kn) {
            const float* kp = k + ((size_t)(b * SS + kt + threadIdx.x)) * DD + hh * DHH;
            const float* vp = v + ((size_t)(b * SS + kt + threadIdx.x)) * DD + hh * DHH;
#pragma unroll
            for (int i = 0; i < DHH; i += 4) {
                *(float4*)&sk[threadIdx.x][i] = *(const float4*)&kp[i];
                *(float4*)&sv[threadIdx.x][i] = *(const float4*)&vp[i];
            }
        }
        __syncthreads();
        for (int j = 0; j < kn; j++) {
            float sc = 0.0f;
#pragma unroll
            for (int i = 0; i < DHH; i++) sc += qv[i] * sk[j][i];
            float nmx = fmaxf(m, sc);
            float scale = __expf(m - nmx);
            float p = __expf(sc - nmx);
            l = l * scale + p;
#pragma unroll
            for (int i = 0; i < DHH; i++) acc[i] = acc[i] * scale + p * sv[j][i];
            m = nmx;
        }
    }
    float inv = 1.0f / l;
    float* op = o + ((size_t)(b * SS + qi)) * DD + hh * DHH;
#pragma unroll
    for (int i = 0; i < DHH; i++) op[i] = acc[i] * inv;
}

// ---------------- kernel 4: fuse wo and w_fc:  W2 = w_fc @ wo,  b2 = b_fc + w_fc @ bo ----------------
__global__ void k_w2(const float* __restrict__ wo, const float* __restrict__ bo,
                     const float* __restrict__ wfc, const float* __restrict__ bfc,
                     float* __restrict__ W2, float* __restrict__ b2) {
    int tid = threadIdx.x;
    if (tid < VV * DD) {
        int vv = tid / DD, i = tid % DD;
        float a = 0.0f;
        for (int j = 0; j < DD; j++) a += wfc[vv * DD + j] * wo[j * DD + i];
        W2[tid] = a;
    } else if (tid < VV * DD + VV) {
        int vv = tid - VV * DD;
        float a = bfc[vv];
        for (int j = 0; j < DD; j++) a += wfc[vv * DD + j] * bo[j];
        b2[vv] = a;
    }
}

// ---------------- kernel 5: out = o @ W2^T + b2 ----------------
__global__ void k_fc(const float* __restrict__ o, const float* __restrict__ W2,
                     const float* __restrict__ b2, float* __restrict__ out) {
    __shared__ float sW[VV * DD];
    __shared__ float sB[VV];
    for (int i = threadIdx.x; i < VV * DD; i += blockDim.x) sW[i] = W2[i];
    if (threadIdx.x < VV) sB[threadIdx.x] = b2[threadIdx.x];
    __syncthreads();

    int idx = blockIdx.x * blockDim.x + threadIdx.x;    // [0, B*S)
    float hv[DD];
#pragma unroll
    for (int i = 0; i < DD; i++) hv[i] = o[(size_t)idx * DD + i];
#pragma unroll
    for (int vv = 0; vv < VV; vv++) {
        float a = sB[vv];
#pragma unroll
        for (int j = 0; j < DD; j++) a += hv[j] * sW[vv * DD + j];
        out[(size_t)idx * VV + vv] = a;
    }
}

extern "C" void kernel_launch(void* const* d_in, const int* in_sizes, int n_in,
                              void* d_out, int out_size, void* d_ws, size_t ws_size,
                              hipStream_t stream) {
    const int*   x    = (const int*)d_in[0];
    const float* mask = (const float*)d_in[1];
    const float* emb  = (const float*)d_in[2];
    const float* pe   = (const float*)d_in[3];
    const float* wq   = (const float*)d_in[4];
    const float* bq   = (const float*)d_in[5];
    const float* wk   = (const float*)d_in[6];
    const float* bk   = (const float*)d_in[7];
    const float* wv   = (const float*)d_in[8];
    const float* bv   = (const float*)d_in[9];
    const float* wo   = (const float*)d_in[10];
    const float* bo   = (const float*)d_in[11];
    const float* wfc  = (const float*)d_in[12];
    const float* bfc  = (const float*)d_in[13];
    float* out = (float*)d_out;

    char* ws = (char*)d_ws;
    const size_t BSD = (size_t)BB * SS * DD * sizeof(float);   // 8 MiB
    int*   e  = (int*)ws;                       // 64 ints
    float* q  = (float*)(ws + 4096);
    float* k  = (float*)(ws + 4096 + BSD);
    float* v  = (float*)(ws + 4096 + 2 * BSD);
    float* o  = (float*)(ws + 4096 + 3 * BSD);
    float* W2 = (float*)(ws + 4096 + 4 * BSD);
    float* b2 = W2 + VV * DD;

    hipLaunchKernelGGL(k_last, dim3(BB), dim3(256), 0, stream, mask, e);
    hipLaunchKernelGGL(k_qkv, dim3(BB * SS / 256), dim3(256), 0, stream,
                       x, emb, pe, wq, bq, wk, bk, wv, bv, e, q, k, v);
    hipLaunchKernelGGL(k_w2, dim3(1), dim3(1024), 0, stream, wo, bo, wfc, bfc, W2, b2);
    hipLaunchKernelGGL(k_attn, dim3(SS / 256, BB * HH), dim3(256), 0, stream, q, k, v, e, o);
    hipLaunchKernelGGL(k_fc, dim3(BB * SS / 256), dim3(256), 0, stream, o, W2, b2, out);
}

// Round 2
// 277.597 us; speedup vs baseline: 1.5409x; 1.5409x over previous
//
#include <hip/hip_runtime.h>
#include <math.h>

#define BB 64
#define SS 1024
#define DD 32
#define HH 2
#define DHH 16
#define VV 28
#define TK 128
#define NSPLIT 4

// ---------------- kernel 1: per-row extended last index ----------------
__global__ void k_last(const float* __restrict__ mask, int* __restrict__ e) {
    int b = blockIdx.x;
    int lm = -1;
    for (int s = threadIdx.x; s < SS; s += blockDim.x) {
        if (mask[b * SS + s] != 0.0f) lm = s;
    }
    __shared__ int red[256];
    red[threadIdx.x] = lm;
    __syncthreads();
    for (int off = 128; off > 0; off >>= 1) {
        if (threadIdx.x < off) red[threadIdx.x] = max(red[threadIdx.x], red[threadIdx.x + off]);
        __syncthreads();
    }
    if (threadIdx.x == 0) {
        int last = red[0];
        int ee = last;
        if (last < SS - 1) ee = min(last + 3, SS - 1);
        e[b] = ee;   // nm[s] = (s <= e)
    }
}

// ---------------- kernel 2: h = (emb[x]+pe)*nm ; q,k,v projections ----------------
__global__ void k_qkv(const int* __restrict__ x, const float* __restrict__ emb,
                      const float* __restrict__ pe,
                      const float* __restrict__ wq, const float* __restrict__ bq,
                      const float* __restrict__ wk, const float* __restrict__ bk,
                      const float* __restrict__ wv, const float* __restrict__ bv,
                      const int* __restrict__ e,
                      float* __restrict__ q, float* __restrict__ k, float* __restrict__ v) {
    __shared__ float sWq[DD * DD], sWk[DD * DD], sWv[DD * DD];
    __shared__ float sBq[DD], sBk[DD], sBv[DD];
    for (int i = threadIdx.x; i < DD * DD; i += blockDim.x) {
        sWq[i] = wq[i]; sWk[i] = wk[i]; sWv[i] = wv[i];
    }
    if (threadIdx.x < DD) {
        sBq[threadIdx.x] = bq[threadIdx.x];
        sBk[threadIdx.x] = bk[threadIdx.x];
        sBv[threadIdx.x] = bv[threadIdx.x];
    }
    __syncthreads();

    int idx = blockIdx.x * blockDim.x + threadIdx.x;    // [0, B*S)
    int b = idx / SS, s = idx % SS;
    float nm = (s <= e[b]) ? 1.0f : 0.0f;
    int tok = x[idx];

    float h[DD];
#pragma unroll
    for (int i = 0; i < DD; i++) h[i] = (emb[tok * DD + i] + pe[s * DD + i]) * nm;

#pragma unroll
    for (int i = 0; i < DD; i++) {
        float aq = sBq[i], ak = sBk[i], av = sBv[i];
#pragma unroll
        for (int j = 0; j < DD; j++) {
            aq += h[j] * sWq[i * DD + j];
            ak += h[j] * sWk[i * DD + j];
            av += h[j] * sWv[i * DD + j];
        }
        q[(size_t)idx * DD + i] = aq;
        k[(size_t)idx * DD + i] = ak;
        v[(size_t)idx * DD + i] = av;
    }
}

// ---------------- kernel 3: split-K flash attention ----------------
// grid (S/256, B*H, NSPLIT), block 256. One thread per (b,h,q,split).
__global__ void k_attn(const float* __restrict__ q, const float* __restrict__ k,
                       const float* __restrict__ v, const int* __restrict__ e,
                       float* __restrict__ pm, float* __restrict__ pl,
                       float* __restrict__ pacc) {
    int bh = blockIdx.y;
    int b = bh / HH, hh = bh % HH;
    int sp = blockIdx.z;
    int qi = blockIdx.x * blockDim.x + threadIdx.x;

    int kmax = e[b] + 1;   // prefix mask => exact truncation
    int chunk = (kmax + NSPLIT - 1) / NSPLIT;
    int k0 = sp * chunk;
    int k1 = min(kmax, k0 + chunk);

    __shared__ float sk[TK][DHH];
    __shared__ float sv[TK][DHH];

    const float* qp = q + ((size_t)(b * SS + qi)) * DD + hh * DHH;
    float qv[DHH];
#pragma unroll
    for (int i = 0; i < DHH; i++) qv[i] = qp[i] * 0.25f;   // 1/sqrt(DH)

    float m = -1e30f, l = 0.0f;
    float acc[DHH];
#pragma unroll
    for (int i = 0; i < DHH; i++) acc[i] = 0.0f;

    for (int kt = k0; kt < k1; kt += TK) {          // trip count wave-uniform
        int kn = min(TK, k1 - kt);
        __syncthreads();
        {
            int r = threadIdx.x & (TK - 1);
            if (r < kn) {
                const float* src = (threadIdx.x < TK ? k : v)
                                   + ((size_t)(b * SS + kt + r)) * DD + hh * DHH;
                float* dst = (threadIdx.x < TK ? &sk[r][0] : &sv[r][0]);
#pragma unroll
                for (int i = 0; i < DHH; i += 4)
                    *(float4*)&dst[i] = *(const float4*)&src[i];
            }
        }
        __syncthreads();
        for (int j = 0; j < kn; j++) {
            // tree-reduced dot: 4 chains of 4 FMAs
            float d0 = qv[0] * sk[j][0], d1 = qv[1] * sk[j][1];
            float d2 = qv[2] * sk[j][2], d3 = qv[3] * sk[j][3];
#pragma unroll
            for (int i = 4; i < DHH; i += 4) {
                d0 += qv[i]     * sk[j][i];
                d1 += qv[i + 1] * sk[j][i + 1];
                d2 += qv[i + 2] * sk[j][i + 2];
                d3 += qv[i + 3] * sk[j][i + 3];
            }
            float sc = (d0 + d1) + (d2 + d3);
            float nmx = fmaxf(m, sc);
            float scale = __expf(m - nmx);
            float p = __expf(sc - nmx);
            l = l * scale + p;
#pragma unroll
            for (int i = 0; i < DHH; i++) acc[i] = acc[i] * scale + p * sv[j][i];
            m = nmx;
        }
    }
    size_t pi = ((size_t)bh * SS + qi) * NSPLIT + sp;
    pm[pi] = m;
    pl[pi] = l;
#pragma unroll
    for (int i = 0; i < DHH; i += 4)
        *(float4*)&pacc[pi * DHH + i] = *(const float4*)&acc[i];
}

// ---------------- kernel 3b: combine split-K partials ----------------
__global__ void k_comb(const float* __restrict__ pm, const float* __restrict__ pl,
                       const float* __restrict__ pacc, float* __restrict__ o) {
    int idx = blockIdx.x * blockDim.x + threadIdx.x;   // [0, B*H*S)
    int bh = idx / SS, qi = idx % SS;
    int b = bh / HH, hh = bh % HH;
    size_t base = (size_t)idx * NSPLIT;

    float m0 = pm[base], m1 = pm[base + 1], m2 = pm[base + 2], m3 = pm[base + 3];
    float M = fmaxf(fmaxf(m0, m1), fmaxf(m2, m3));
    float s0 = __expf(m0 - M), s1 = __expf(m1 - M);
    float s2 = __expf(m2 - M), s3 = __expf(m3 - M);
    float l = pl[base] * s0 + pl[base + 1] * s1 + pl[base + 2] * s2 + pl[base + 3] * s3;

    float acc[DHH];
#pragma unroll
    for (int i = 0; i < DHH; i++) {
        acc[i] = pacc[(base + 0) * DHH + i] * s0 + pacc[(base + 1) * DHH + i] * s1
               + pacc[(base + 2) * DHH + i] * s2 + pacc[(base + 3) * DHH + i] * s3;
    }
    float inv = 1.0f / l;
    float* op = o + ((size_t)(b * SS + qi)) * DD + hh * DHH;
#pragma unroll
    for (int i = 0; i < DHH; i++) op[i] = acc[i] * inv;
}

// ---------------- kernel 4: fuse wo and w_fc ----------------
__global__ void k_w2(const float* __restrict__ wo, const float* __restrict__ bo,
                     const float* __restrict__ wfc, const float* __restrict__ bfc,
                     float* __restrict__ W2, float* __restrict__ b2) {
    int tid = threadIdx.x;
    if (tid < VV * DD) {
        int vv = tid / DD, i = tid % DD;
        float a = 0.0f;
        for (int j = 0; j < DD; j++) a += wfc[vv * DD + j] * wo[j * DD + i];
        W2[tid] = a;
    } else if (tid < VV * DD + VV) {
        int vv = tid - VV * DD;
        float a = bfc[vv];
        for (int j = 0; j < DD; j++) a += wfc[vv * DD + j] * bo[j];
        b2[vv] = a;
    }
}

// ---------------- kernel 5: out = o @ W2^T + b2 ----------------
__global__ void k_fc(const float* __restrict__ o, const float* __restrict__ W2,
                     const float* __restrict__ b2, float* __restrict__ out) {
    __shared__ float sW[VV * DD];
    __shared__ float sB[VV];
    for (int i = threadIdx.x; i < VV * DD; i += blockDim.x) sW[i] = W2[i];
    if (threadIdx.x < VV) sB[threadIdx.x] = b2[threadIdx.x];
    __syncthreads();

    int idx = blockIdx.x * blockDim.x + threadIdx.x;    // [0, B*S)
    float hv[DD];
#pragma unroll
    for (int i = 0; i < DD; i++) hv[i] = o[(size_t)idx * DD + i];
#pragma unroll
    for (int vv = 0; vv < VV; vv++) {
        float a = sB[vv];
#pragma unroll
        for (int j = 0; j < DD; j++) a += hv[j] * sW[vv * DD + j];
        out[(size_t)idx * VV + vv] = a;
    }
}

extern "C" void kernel_launch(void* const* d_in, const int* in_sizes, int n_in,
                              void* d_out, int out_size, void* d_ws, size_t ws_size,
                              hipStream_t stream) {
    const int*   x    = (const int*)d_in[0];
    const float* mask = (const float*)d_in[1];
    const float* emb  = (const float*)d_in[2];
    const float* pe   = (const float*)d_in[3];
    const float* wq   = (const float*)d_in[4];
    const float* bq   = (const float*)d_in[5];
    const float* wk   = (const float*)d_in[6];
    const float* bk   = (const float*)d_in[7];
    const float* wv   = (const float*)d_in[8];
    const float* bv   = (const float*)d_in[9];
    const float* wo   = (const float*)d_in[10];
    const float* bo   = (const float*)d_in[11];
    const float* wfc  = (const float*)d_in[12];
    const float* bfc  = (const float*)d_in[13];
    float* out = (float*)d_out;

    char* ws = (char*)d_ws;
    const size_t BSD = (size_t)BB * SS * DD * sizeof(float);        // 8 MiB
    const size_t NQ  = (size_t)BB * HH * SS;                        // 131072
    int*   e    = (int*)ws;                                         // 64 ints
    float* q    = (float*)(ws + 4096);
    float* k    = (float*)(ws + 4096 + BSD);
    float* v    = (float*)(ws + 4096 + 2 * BSD);
    float* o    = (float*)(ws + 4096 + 3 * BSD);
    float* W2   = (float*)(ws + 4096 + 4 * BSD);
    float* b2   = W2 + VV * DD;
    float* pm   = (float*)(ws + 4096 + 4 * BSD + 65536);
    float* pl   = pm + NQ * NSPLIT;                                 // +2 MiB
    float* pacc = pl + NQ * NSPLIT;                                 // +2 MiB, then 32 MiB

    hipLaunchKernelGGL(k_last, dim3(BB), dim3(256), 0, stream, mask, e);
    hipLaunchKernelGGL(k_qkv, dim3(BB * SS / 256), dim3(256), 0, stream,
                       x, emb, pe, wq, bq, wk, bk, wv, bv, e, q, k, v);
    hipLaunchKernelGGL(k_w2, dim3(1), dim3(1024), 0, stream, wo, bo, wfc, bfc, W2, b2);
    hipLaunchKernelGGL(k_attn, dim3(SS / 256, BB * HH, NSPLIT), dim3(256), 0, stream,
                       q, k, v, e, pm, pl, pacc);
    hipLaunchKernelGGL(k_comb, dim3(BB * HH * SS / 256), dim3(256), 0, stream,
                       pm, pl, pacc, o);
    hipLaunchKernelGGL(k_fc, dim3(BB * SS / 256), dim3(256), 0, stream, o, W2, b2, out);
}